// Round 5
// baseline (858.793 us; speedup 1.0000x reference)
//
#include <hip/hip_runtime.h>
#include <math.h>

#define B_ 2
#define C_ 256
#define L_ 4096
#define BL_ 8192
#define DEPTH_ 4
#define CK_ 64   // chunks per sequence
#define CL_ 64   // chunk length
#define XR_ 8    // rows per xproj block

typedef __attribute__((ext_vector_type(8))) short bf16x8;
typedef __attribute__((ext_vector_type(4))) float f32x4;
#define MFMA16 __builtin_amdgcn_mfma_f32_16x16x32_bf16

__device__ __forceinline__ float silu_(float x){ return x/(1.f+__expf(-x)); }
__device__ __forceinline__ float softplus_(float x){ return fmaxf(x,0.f)+log1pf(__expf(-fabsf(x))); }
__device__ __forceinline__ unsigned short f2b_(float f){
    union{float f;unsigned u;}v; v.f=f;
    unsigned r=(v.u + 0x7fffu + ((v.u>>16)&1u))>>16;
    return (unsigned short)r;
}

// ---------------- fp32 -> bf16 weight conversion ----------------
__global__ __launch_bounds__(256) void k_w2b(const float* __restrict__ src, unsigned short* __restrict__ dst)
{
    int i=blockIdx.x*256+threadIdx.x;
    float4 v=((const float4*)src)[i];
    ushort4 o; o.x=f2b_(v.x); o.y=f2b_(v.y); o.z=f2b_(v.z); o.w=f2b_(v.w);
    ((ushort4*)dst)[i]=o;
}

// ---------------- transpose in: x (B,C,D,H,W) -> t [B][L][C], l=(h*16+w)*16+d ----------------
__global__ __launch_bounds__(256) void k_t_in(const float* __restrict__ x, float* __restrict__ t)
{
    __shared__ float tile[16*257];
    int blk=blockIdx.x, b=blk>>8, d=(blk>>4)&15, h=blk&15;
    int tid=threadIdx.x;
    int w2=tid&15;
    for(int p=0;p<16;p++){
        int c=(tid>>4)+16*p;
        tile[w2*257+c]=x[((size_t)(b*C_+c))*4096 + d*256 + h*16 + w2];
    }
    __syncthreads();
    for(int k=0;k<16;k++){
        t[((size_t)b*L_+(h*16+k)*16+d)*C_+tid]=tile[k*257+tid];
    }
}

// ---------------- LN1: t -> hb (bf16 [M][256]) ----------------
__global__ __launch_bounds__(256) void k_ln(
    const float* __restrict__ t, const float* __restrict__ g,
    const float* __restrict__ be, unsigned short* __restrict__ hb)
{
    int wv=threadIdx.x>>6, lane=threadIdx.x&63;
    int row=blockIdx.x*4+wv;
    float4 v=((const float4*)(t+(size_t)row*C_))[lane];
    float s=v.x+v.y+v.z+v.w;
    float ss=v.x*v.x+v.y*v.y+v.z*v.z+v.w*v.w;
    #pragma unroll
    for(int m=1;m<64;m<<=1){ s+=__shfl_xor(s,m); ss+=__shfl_xor(ss,m); }
    float mn=s*(1.f/256.f);
    float rs=rsqrtf(ss*(1.f/256.f)-mn*mn+1e-5f);
    float4 gg=((const float4*)g)[lane];
    float4 bb=((const float4*)be)[lane];
    ushort4 o;
    o.x=f2b_((v.x-mn)*rs*gg.x+bb.x);
    o.y=f2b_((v.y-mn)*rs*gg.y+bb.y);
    o.z=f2b_((v.z-mn)*rs*gg.z+bb.z);
    o.w=f2b_((v.w-mn)*rs*gg.w+bb.w);
    ((ushort4*)(hb+(size_t)row*C_))[lane]=o;
}

// ---------------- MFMA GEMM: xs|z[m][n] = hb[m][k] * Wt[n][k] ; N=512 split ----------------
__global__ __launch_bounds__(256) void k_gemm_in(
    const unsigned short* __restrict__ Ab, const unsigned short* __restrict__ Wb,
    float* __restrict__ xs, float* __restrict__ z)
{
    int wv=threadIdx.x>>6, lane=threadIdx.x&63;
    int m0=blockIdx.x*64+(wv>>1)*32;
    int n0=blockIdx.y*64+(wv&1)*32;
    int la=lane&15, kg=lane>>4;
    f32x4 acc[2][2];
    #pragma unroll
    for(int i=0;i<2;i++)
        #pragma unroll
        for(int j=0;j<2;j++) acc[i][j]=(f32x4){0.f,0.f,0.f,0.f};
    const unsigned short* a0p=Ab+(size_t)(m0+la)*C_+kg*8;
    const unsigned short* a1p=Ab+(size_t)(m0+16+la)*C_+kg*8;
    const unsigned short* b0p=Wb+(size_t)(n0+la)*C_+kg*8;
    const unsigned short* b1p=Wb+(size_t)(n0+16+la)*C_+kg*8;
    #pragma unroll
    for(int kk=0;kk<C_;kk+=32){
        bf16x8 a0=*(const bf16x8*)(a0p+kk);
        bf16x8 a1=*(const bf16x8*)(a1p+kk);
        bf16x8 b0=*(const bf16x8*)(b0p+kk);
        bf16x8 b1=*(const bf16x8*)(b1p+kk);
        acc[0][0]=MFMA16(a0,b0,acc[0][0],0,0,0);
        acc[0][1]=MFMA16(a0,b1,acc[0][1],0,0,0);
        acc[1][0]=MFMA16(a1,b0,acc[1][0],0,0,0);
        acc[1][1]=MFMA16(a1,b1,acc[1][1],0,0,0);
    }
    #pragma unroll
    for(int mi=0;mi<2;mi++)
        #pragma unroll
        for(int nj=0;nj<2;nj++)
            #pragma unroll
            for(int r=0;r<4;r++){
                int m=m0+mi*16+kg*4+r;
                int n=n0+nj*16+la;
                float val=acc[mi][nj][r];
                if(n<256) xs[(size_t)m*C_+n]=val;
                else      z [(size_t)m*C_+(n-256)]=val;
            }
}

// ---------------- MFMA GEMM + residual: t[m][n] += y2b[m][k] * Wt[n][k] ----------------
__global__ __launch_bounds__(256) void k_gemm_out(
    const unsigned short* __restrict__ Ab, const unsigned short* __restrict__ Wb,
    float* __restrict__ t)
{
    int wv=threadIdx.x>>6, lane=threadIdx.x&63;
    int m0=blockIdx.x*64+(wv>>1)*32;
    int n0=blockIdx.y*64+(wv&1)*32;
    int la=lane&15, kg=lane>>4;
    f32x4 acc[2][2];
    #pragma unroll
    for(int i=0;i<2;i++)
        #pragma unroll
        for(int j=0;j<2;j++) acc[i][j]=(f32x4){0.f,0.f,0.f,0.f};
    const unsigned short* a0p=Ab+(size_t)(m0+la)*C_+kg*8;
    const unsigned short* a1p=Ab+(size_t)(m0+16+la)*C_+kg*8;
    const unsigned short* b0p=Wb+(size_t)(n0+la)*C_+kg*8;
    const unsigned short* b1p=Wb+(size_t)(n0+16+la)*C_+kg*8;
    #pragma unroll
    for(int kk=0;kk<C_;kk+=32){
        bf16x8 a0=*(const bf16x8*)(a0p+kk);
        bf16x8 a1=*(const bf16x8*)(a1p+kk);
        bf16x8 b0=*(const bf16x8*)(b0p+kk);
        bf16x8 b1=*(const bf16x8*)(b1p+kk);
        acc[0][0]=MFMA16(a0,b0,acc[0][0],0,0,0);
        acc[0][1]=MFMA16(a0,b1,acc[0][1],0,0,0);
        acc[1][0]=MFMA16(a1,b0,acc[1][0],0,0,0);
        acc[1][1]=MFMA16(a1,b1,acc[1][1],0,0,0);
    }
    #pragma unroll
    for(int mi=0;mi<2;mi++)
        #pragma unroll
        for(int nj=0;nj<2;nj++)
            #pragma unroll
            for(int r=0;r<4;r++){
                int m=m0+mi*16+kg*4+r;
                int n=n0+nj*16+la;
                float* tp=t+(size_t)m*C_+n;
                *tp=*tp+acc[mi][nj][r];
            }
}

// ---------------- depthwise conv3x3x3 + bias + SiLU + flip-write -> seq ----------------
__global__ __launch_bounds__(256) void k_conv(
    const float* __restrict__ xs, const float* __restrict__ cw,
    const float* __restrict__ cb, float* __restrict__ seq, int ori)
{
    __shared__ float wl[256*27];
    int tid=threadIdx.x;
    for(int j=tid;j<256*27;j+=256) wl[j]=cw[j];
    int bl=blockIdx.x;
    int b=bl>>12, l=bl&4095;
    int d=l&15, w=(l>>4)&15, h=l>>8;
    __syncthreads();
    const float* base=xs+((size_t)b*L_)*C_+tid;
    const float* wp=wl+tid*27;
    float acc=cb[tid];
    #pragma unroll
    for(int kh=0;kh<3;kh++){
        int hh=h+kh-1; if((unsigned)hh>=16u) continue;
        #pragma unroll
        for(int kw=0;kw<3;kw++){
            int ww=w+kw-1; if((unsigned)ww>=16u) continue;
            #pragma unroll
            for(int kd=0;kd<3;kd++){
                int dd=d+kd-1; if((unsigned)dd>=16u) continue;
                acc=fmaf(wp[(kh*3+kw)*3+kd], base[(size_t)((hh*16+ww)*16+dd)*C_], acc);
            }
        }
    }
    acc=silu_(acc);
    int hf=(ori&1)?15-h:h;
    int wf=(ori&2)?15-w:w;
    int df=(ori&4)?15-d:d;
    seq[((size_t)b*L_+(hf*16+wf)*16+df)*C_+tid]=acc;
}

// ---------------- xproj (48 cols) + dt proj (softplus) + emit scan-major dtT/sxT ----------------
// 8-row tiles, grid 1024 (4 blocks/CU): occupancy-limited fix for the R4 bottleneck
__global__ __launch_bounds__(256) void k_xproj(
    const float* __restrict__ seq, const float* __restrict__ xw,
    const float* __restrict__ dtw, const float* __restrict__ dtbias,
    float* __restrict__ dtT, float* __restrict__ sxT, float* __restrict__ BC)
{
    __shared__ float hb[XR_][260];     // +4 pad: row shifts banks by 4, kills 4-way conflict
    __shared__ float dbl[XR_][48];
    int tid=threadIdx.x;
    size_t row0=(size_t)blockIdx.x*XR_;
    int b=(int)(row0>>12), lloc=(int)(row0&4095);
    // load 8 rows x 256: thread (r=tid>>5, 8 floats at col (tid&31)*8)
    {
        int r=tid>>5, c0=(tid&31)*8;
        const float4* sp=(const float4*)(seq+(row0+r)*C_+c0);
        float4 v0=sp[0], v1=sp[1];
        *(float4*)&hb[r][c0]=v0;
        *(float4*)&hb[r][c0+4]=v1;
    }
    __syncthreads();
    // phase 1: 48-col projection. thread (r=tid>>5, q=tid&31): out j=q, and j=q+32 if q<16
    {
        int r=tid>>5, q=tid&31;
        const float4* wa=(const float4*)(xw+(size_t)q*C_);
        const float4* wb=(const float4*)(xw+(size_t)(q+32)*C_);
        float a=0.f,b2=0.f;
        bool two=(q<16);
        for(int k4=0;k4<64;k4++){
            const float4 hv=*(const float4*)&hb[r][k4*4];
            float4 xa=wa[k4];
            a=fmaf(hv.x,xa.x,fmaf(hv.y,xa.y,fmaf(hv.z,xa.z,fmaf(hv.w,xa.w,a))));
            if(two){
                float4 xb=wb[k4];
                b2=fmaf(hv.x,xb.x,fmaf(hv.y,xb.y,fmaf(hv.z,xb.z,fmaf(hv.w,xb.w,b2))));
            }
        }
        dbl[r][q]=a;
        if(two) dbl[r][q+32]=b2;
    }
    __syncthreads();
    // BC emission: thread (r=tid>>5, j2=tid&31) -> linear coalesced
    {
        int r=tid>>5, j2=tid&31;
        BC[(row0+r)*32+j2]=dbl[r][16+j2];
    }
    // sxT emission: thread c writes 8 l values (2 float4)
    {
        float* sp = sxT + ((size_t)(b*C_+tid))*L_ + lloc;
        ((float4*)sp)[0]=make_float4(hb[0][tid],hb[1][tid],hb[2][tid],hb[3][tid]);
        ((float4*)sp)[1]=make_float4(hb[4][tid],hb[5][tid],hb[6][tid],hb[7][tid]);
    }
    // dt projection + softplus: thread c over 8 rows
    float4 w0=((const float4*)(dtw+(size_t)tid*16))[0];
    float4 w1=((const float4*)(dtw+(size_t)tid*16))[1];
    float4 w2=((const float4*)(dtw+(size_t)tid*16))[2];
    float4 w3=((const float4*)(dtw+(size_t)tid*16))[3];
    float bb=dtbias[tid];
    float dts[XR_];
    #pragma unroll
    for(int r2=0;r2<XR_;r2++){
        float acc=bb;
        acc=fmaf(dbl[r2][0],w0.x,acc); acc=fmaf(dbl[r2][1],w0.y,acc);
        acc=fmaf(dbl[r2][2],w0.z,acc); acc=fmaf(dbl[r2][3],w0.w,acc);
        acc=fmaf(dbl[r2][4],w1.x,acc); acc=fmaf(dbl[r2][5],w1.y,acc);
        acc=fmaf(dbl[r2][6],w1.z,acc); acc=fmaf(dbl[r2][7],w1.w,acc);
        acc=fmaf(dbl[r2][8],w2.x,acc); acc=fmaf(dbl[r2][9],w2.y,acc);
        acc=fmaf(dbl[r2][10],w2.z,acc); acc=fmaf(dbl[r2][11],w2.w,acc);
        acc=fmaf(dbl[r2][12],w3.x,acc); acc=fmaf(dbl[r2][13],w3.y,acc);
        acc=fmaf(dbl[r2][14],w3.z,acc); acc=fmaf(dbl[r2][15],w3.w,acc);
        dts[r2]=softplus_(acc);
    }
    float* dp = dtT + ((size_t)(b*C_+tid))*L_ + lloc;
    ((float4*)dp)[0]=make_float4(dts[0],dts[1],dts[2],dts[3]);
    ((float4*)dp)[1]=make_float4(dts[4],dts[5],dts[6],dts[7]);
}

// ---------------- chunked selective scan ----------------
__global__ __launch_bounds__(256) void k_scan1(
    const float* __restrict__ dtT, const float* __restrict__ sxT,
    const float* __restrict__ BC, const float* __restrict__ A_log,
    float* __restrict__ Ap, float* __restrict__ Ho)
{
    int wv=threadIdx.x>>6, lane=threadIdx.x&63;
    int grp=lane>>4, n=lane&15;
    int blk=blockIdx.x, pg=blk>>4, ck=(blk&15)*4+wv;
    int pair=pg*4+grp, b=pair>>8, c=pair&255;
    float An=-__expf(A_log[c*16+n]);
    int l0=ck*CL_;
    const float4* dp=(const float4*)(dtT+((size_t)(b*C_+c))*L_+l0);
    const float4* xp=(const float4*)(sxT+((size_t)(b*C_+c))*L_+l0);
    const float* bcp=BC+((size_t)b*L_+l0)*32+n;
    float carry=0.f, sdt=0.f;
    #pragma unroll
    for(int q=0;q<CL_/4;q++){
        float4 d4=dp[q], x4=xp[q];
        float bv;
        bv=bcp[(4*q+0)*32];{float dA=__expf(d4.x*An);carry=fmaf(dA,carry,d4.x*bv*x4.x);sdt+=d4.x;}
        bv=bcp[(4*q+1)*32];{float dA=__expf(d4.y*An);carry=fmaf(dA,carry,d4.y*bv*x4.y);sdt+=d4.y;}
        bv=bcp[(4*q+2)*32];{float dA=__expf(d4.z*An);carry=fmaf(dA,carry,d4.z*bv*x4.z);sdt+=d4.z;}
        bv=bcp[(4*q+3)*32];{float dA=__expf(d4.w*An);carry=fmaf(dA,carry,d4.w*bv*x4.w);sdt+=d4.w;}
    }
    int idx=(pair*CK_+ck)*16+n;
    Ap[idx]=__expf(An*sdt); Ho[idx]=carry;
}

__global__ __launch_bounds__(256) void k_scan2(
    const float* __restrict__ Ap, const float* __restrict__ Ho, float* __restrict__ Sb)
{
    int gid=blockIdx.x*256+threadIdx.x;
    int pair=gid>>4, n=gid&15;
    float S=0.f;
    #pragma unroll
    for(int ck=0;ck<CK_;ck++){
        int idx=(pair*CK_+ck)*16+n;
        Sb[idx]=S;
        S=fmaf(Ap[idx],S,Ho[idx]);
    }
}

__global__ __launch_bounds__(256) void k_scan3(
    const float* __restrict__ dtT, const float* __restrict__ sxT,
    const float* __restrict__ BC, const float* __restrict__ A_log,
    const float* __restrict__ Dsk, const float* __restrict__ Sb,
    float* __restrict__ y)
{
    int wv=threadIdx.x>>6, lane=threadIdx.x&63;
    int grp=lane>>4, n=lane&15;
    int blk=blockIdx.x, pg=blk>>4, ck=(blk&15)*4+wv;
    int pair=pg*4+grp, b=pair>>8, c=pair&255;
    float An=-__expf(A_log[c*16+n]);
    float Dc=Dsk[c];
    int l0=ck*CL_;
    const float4* dp=(const float4*)(dtT+((size_t)(b*C_+c))*L_+l0);
    const float4* xp=(const float4*)(sxT+((size_t)(b*C_+c))*L_+l0);
    const float* bcp=BC+((size_t)b*L_+l0)*32;
    float* yp=y+((size_t)b*L_+l0)*C_+c;
    float carry=Sb[(pair*CK_+ck)*16+n];
    #pragma unroll
    for(int q=0;q<CL_/4;q++){
        float4 d4=dp[q], x4=xp[q];
        #pragma unroll
        for(int s2=0;s2<4;s2++){
            int st=4*q+s2;
            float dtv=(s2==0)?d4.x:(s2==1)?d4.y:(s2==2)?d4.z:d4.w;
            float xv =(s2==0)?x4.x:(s2==1)?x4.y:(s2==2)?x4.z:x4.w;
            float bv=bcp[st*32+n];
            float cv=bcp[st*32+16+n];
            float dA=__expf(dtv*An);
            carry=fmaf(dA,carry,dtv*bv*xv);
            float part=carry*cv;
            part+=__shfl_xor(part,1);
            part+=__shfl_xor(part,2);
            part+=__shfl_xor(part,4);
            part+=__shfl_xor(part,8);
            if(n==0) yp[(size_t)st*C_]=fmaf(Dc,xv,part);
        }
    }
}

// ---------------- unflip + out-LN + gate by SiLU(z) -> y2b (bf16) ----------------
__global__ __launch_bounds__(256) void k_post(
    const float* __restrict__ y, const float* __restrict__ z,
    const float* __restrict__ og, const float* __restrict__ ob,
    unsigned short* __restrict__ y2b, int ori)
{
    __shared__ float red[8];
    int c=threadIdx.x;
    int bl=blockIdx.x, b=bl>>12, l=bl&4095;
    int d=l&15, w=(l>>4)&15, h=l>>8;
    int hf=(ori&1)?15-h:h, wf=(ori&2)?15-w:w, df=(ori&4)?15-d:d;
    int lf=(hf*16+wf)*16+df;
    float v=y[((size_t)b*L_+lf)*C_+c];
    float s=v, ss=v*v;
    #pragma unroll
    for(int m=32;m>=1;m>>=1){ s+=__shfl_xor(s,m); ss+=__shfl_xor(ss,m); }
    if((c&63)==0){ red[(c>>6)*2]=s; red[(c>>6)*2+1]=ss; }
    __syncthreads();
    s=red[0]+red[2]+red[4]+red[6];
    ss=red[1]+red[3]+red[5]+red[7];
    float mn=s*(1.f/256.f);
    float rstd=rsqrtf(ss*(1.f/256.f)-mn*mn+1e-5f);
    float yn=(v-mn)*rstd*og[c]+ob[c];
    float zv=z[((size_t)b*L_+l)*C_+c];
    y2b[((size_t)b*L_+l)*C_+c]=f2b_(yn*silu_(zv));
}

// ---------------- final LN + transpose out ----------------
__global__ __launch_bounds__(256) void k_final(
    const float* __restrict__ t, const float* __restrict__ pg,
    const float* __restrict__ pb, float* __restrict__ out)
{
    __shared__ float tile[16*257];
    __shared__ float mrs[16][2];
    int blk=blockIdx.x, b=blk>>8, d=(blk>>4)&15, h=blk&15;
    int tid=threadIdx.x;
    for(int w2=0;w2<16;w2++){
        tile[w2*257+tid]=t[((size_t)b*L_+(h*16+w2)*16+d)*C_+tid];
    }
    __syncthreads();
    int r=tid>>4, p=tid&15;
    float s=0.f, ss=0.f;
    #pragma unroll
    for(int k=0;k<16;k++){ float v=tile[r*257+k*16+p]; s+=v; ss+=v*v; }
    #pragma unroll
    for(int m=1;m<16;m<<=1){ s+=__shfl_xor(s,m); ss+=__shfl_xor(ss,m); }
    if(p==0){ float mn=s*(1.f/256.f); mrs[r][0]=mn; mrs[r][1]=rsqrtf(ss*(1.f/256.f)-mn*mn+1e-5f); }
    __syncthreads();
    int w2=tid&15;
    for(int p2=0;p2<16;p2++){
        int c=(tid>>4)+16*p2;
        float v=tile[w2*257+c];
        float vn=(v-mrs[w2][0])*mrs[w2][1]*pg[c]+pb[c];
        out[((size_t)(b*C_+c))*4096 + d*256 + h*16 + w2]=vn;
    }
}

extern "C" void kernel_launch(void* const* d_in, const int* in_sizes, int n_in,
                              void* d_out, int out_size, void* d_ws, size_t ws_size,
                              hipStream_t stream)
{
    (void)in_sizes; (void)n_in; (void)out_size; (void)ws_size;
    const float* x      =(const float*)d_in[0];
    const float* in_w   =(const float*)d_in[1];
    const float* conv_w =(const float*)d_in[2];
    const float* conv_b =(const float*)d_in[3];
    const float* xproj_w=(const float*)d_in[4];
    const float* dt_w   =(const float*)d_in[5];
    const float* dt_b   =(const float*)d_in[6];
    const float* A_log  =(const float*)d_in[7];
    const float* D_skip =(const float*)d_in[8];
    const float* on_g   =(const float*)d_in[9];
    const float* on_b   =(const float*)d_in[10];
    const float* out_w  =(const float*)d_in[11];
    const float* ln1_g  =(const float*)d_in[12];
    const float* ln1_b  =(const float*)d_in[13];
    const float* post_g =(const float*)d_in[14];
    const float* post_b =(const float*)d_in[15];
    float* out=(float*)d_out;
    float* ws=(float*)d_ws;

    const size_t NBL=(size_t)BL_*C_;     // 2,097,152 elems
    float* t   = ws;                      // residual stream [B][L][C]
    float* xs  = ws +   NBL;              // in-proj x-path
    float* z   = ws + 2*NBL;
    float* seq = ws + 3*NBL;              // conv output [l][c]; later y
    float* dtT = ws + 4*NBL;              // dt, scan-major [b][c][l]
    float* BC  = ws + 5*NBL;              // [B*L][32] (Bm | Cm)
    float* Ap  = BC + (size_t)BL_*32;
    float* Ho  = Ap + 512*CK_*16;
    float* Sb  = Ho + 512*CK_*16;
    unsigned short* hb  = (unsigned short*)(Sb + 512*CK_*16);  // bf16 LN'd activations [M][256]
    unsigned short* y2b = hb  + NBL;                           // bf16 gated output [M][256]
    unsigned short* wbI = y2b + NBL;                           // bf16 in_w  (4*512*256)
    unsigned short* wbO = wbI + (size_t)DEPTH_*512*C_;         // bf16 out_w (4*256*256)
    float* sxT = out;                     // seq, scan-major [b][c][l] — aliases d_out (dead until k_final)

    k_w2b<<<DEPTH_*512*C_/1024,256,0,stream>>>(in_w, wbI);
    k_w2b<<<DEPTH_*C_*C_/1024,256,0,stream>>>(out_w, wbO);
    k_t_in<<<512,256,0,stream>>>(x,t);
    for(int i=0;i<DEPTH_;i++){
        int ori=i&7;
        k_ln<<<2048,256,0,stream>>>(t, ln1_g+i*256, ln1_b+i*256, hb);
        k_gemm_in<<<dim3(128,8),256,0,stream>>>(hb, wbI+(size_t)i*512*C_, xs, z);
        k_conv<<<8192,256,0,stream>>>(xs, conv_w+(size_t)i*6912, conv_b+i*256, seq, ori);
        k_xproj<<<BL_/XR_,256,0,stream>>>(seq, xproj_w+(size_t)i*12288, dt_w+(size_t)i*4096, dt_b+i*256, dtT, sxT, BC);
        k_scan1<<<2048,256,0,stream>>>(dtT, sxT, BC, A_log+(size_t)i*4096, Ap, Ho);
        k_scan2<<<32,256,0,stream>>>(Ap, Ho, Sb);
        k_scan3<<<2048,256,0,stream>>>(dtT, sxT, BC, A_log+(size_t)i*4096, D_skip+i*256, Sb, seq);
        k_post<<<8192,256,0,stream>>>(seq, z, on_g+i*256, on_b+i*256, y2b, ori);
        k_gemm_out<<<dim3(128,4),256,0,stream>>>(y2b, wbO+(size_t)i*C_*C_, t);
    }
    k_final<<<512,256,0,stream>>>(t, post_g, post_b, out);
}

// Round 8
// 750.062 us; speedup vs baseline: 1.1450x; 1.1450x over previous
//
#include <hip/hip_runtime.h>
#include <math.h>

#define B_ 2
#define C_ 256
#define L_ 4096
#define BL_ 8192
#define DEPTH_ 4
#define CK_ 64   // chunks per sequence
#define CL_ 64   // chunk length

typedef __attribute__((ext_vector_type(8))) short bf16x8;
typedef __attribute__((ext_vector_type(4))) float f32x4;
#define MFMA16 __builtin_amdgcn_mfma_f32_16x16x32_bf16

__device__ __forceinline__ float silu_(float x){ return x/(1.f+__expf(-x)); }
__device__ __forceinline__ float softplus_(float x){ return fmaxf(x,0.f)+log1pf(__expf(-fabsf(x))); }
__device__ __forceinline__ unsigned short f2b_(float f){
    union{float f;unsigned u;}v; v.f=f;
    unsigned r=(v.u + 0x7fffu + ((v.u>>16)&1u))>>16;
    return (unsigned short)r;
}

// ---------------- fp32 -> bf16 weight conversion ----------------
__global__ __launch_bounds__(256) void k_w2b(const float* __restrict__ src, unsigned short* __restrict__ dst)
{
    int i=blockIdx.x*256+threadIdx.x;
    float4 v=((const float4*)src)[i];
    ushort4 o; o.x=f2b_(v.x); o.y=f2b_(v.y); o.z=f2b_(v.z); o.w=f2b_(v.w);
    ((ushort4*)dst)[i]=o;
}

// ---------------- composed dt weight: W_eff[i][c][k] = sum_j dt_w[i][c][j]*xw[i][j][k] -> bf16 ----------------
__global__ __launch_bounds__(256) void k_wdt(
    const float* __restrict__ dtw, const float* __restrict__ xw,
    unsigned short* __restrict__ wdtb)
{
    int blk=blockIdx.x;          // i*256 + c
    int i=blk>>8, c=blk&255, k=threadIdx.x;
    const float* dr=dtw+((size_t)i*C_+c)*16;
    const float* xr=xw+(size_t)i*48*C_+k;
    float acc=0.f;
    #pragma unroll
    for(int j=0;j<16;j++) acc=fmaf(dr[j], xr[(size_t)j*C_], acc);
    wdtb[((size_t)i*C_+c)*C_+k]=f2b_(acc);
}

// ---------------- transpose in: x (B,C,D,H,W) -> t [B][L][C], l=(h*16+w)*16+d ----------------
__global__ __launch_bounds__(256) void k_t_in(const float* __restrict__ x, float* __restrict__ t)
{
    __shared__ float tile[16*257];
    int blk=blockIdx.x, b=blk>>8, d=(blk>>4)&15, h=blk&15;
    int tid=threadIdx.x;
    int w2=tid&15;
    for(int p=0;p<16;p++){
        int c=(tid>>4)+16*p;
        tile[w2*257+c]=x[((size_t)(b*C_+c))*4096 + d*256 + h*16 + w2];
    }
    __syncthreads();
    for(int k=0;k<16;k++){
        t[((size_t)b*L_+(h*16+k)*16+d)*C_+tid]=tile[k*257+tid];
    }
}

// ---------------- LN1: t -> hb (bf16 [M][256]) ----------------
__global__ __launch_bounds__(256) void k_ln(
    const float* __restrict__ t, const float* __restrict__ g,
    const float* __restrict__ be, unsigned short* __restrict__ hb)
{
    int wv=threadIdx.x>>6, lane=threadIdx.x&63;
    int row=blockIdx.x*4+wv;
    float4 v=((const float4*)(t+(size_t)row*C_))[lane];
    float s=v.x+v.y+v.z+v.w;
    float ss=v.x*v.x+v.y*v.y+v.z*v.z+v.w*v.w;
    #pragma unroll
    for(int m=1;m<64;m<<=1){ s+=__shfl_xor(s,m); ss+=__shfl_xor(ss,m); }
    float mn=s*(1.f/256.f);
    float rs=rsqrtf(ss*(1.f/256.f)-mn*mn+1e-5f);
    float4 gg=((const float4*)g)[lane];
    float4 bb=((const float4*)be)[lane];
    ushort4 o;
    o.x=f2b_((v.x-mn)*rs*gg.x+bb.x);
    o.y=f2b_((v.y-mn)*rs*gg.y+bb.y);
    o.z=f2b_((v.z-mn)*rs*gg.z+bb.z);
    o.w=f2b_((v.w-mn)*rs*gg.w+bb.w);
    ((ushort4*)(hb+(size_t)row*C_))[lane]=o;
}

// ---------------- MFMA GEMM: xs|z[m][n] = hb[m][k] * Wt[n][k] ; N=512 split ----------------
__global__ __launch_bounds__(256) void k_gemm_in(
    const unsigned short* __restrict__ Ab, const unsigned short* __restrict__ Wb,
    float* __restrict__ xs, float* __restrict__ z)
{
    int wv=threadIdx.x>>6, lane=threadIdx.x&63;
    int m0=blockIdx.x*64+(wv>>1)*32;
    int n0=blockIdx.y*64+(wv&1)*32;
    int la=lane&15, kg=lane>>4;
    f32x4 acc[2][2];
    #pragma unroll
    for(int i=0;i<2;i++)
        #pragma unroll
        for(int j=0;j<2;j++) acc[i][j]=(f32x4){0.f,0.f,0.f,0.f};
    const unsigned short* a0p=Ab+(size_t)(m0+la)*C_+kg*8;
    const unsigned short* a1p=Ab+(size_t)(m0+16+la)*C_+kg*8;
    const unsigned short* b0p=Wb+(size_t)(n0+la)*C_+kg*8;
    const unsigned short* b1p=Wb+(size_t)(n0+16+la)*C_+kg*8;
    #pragma unroll
    for(int kk=0;kk<C_;kk+=32){
        bf16x8 a0=*(const bf16x8*)(a0p+kk);
        bf16x8 a1=*(const bf16x8*)(a1p+kk);
        bf16x8 b0=*(const bf16x8*)(b0p+kk);
        bf16x8 b1=*(const bf16x8*)(b1p+kk);
        acc[0][0]=MFMA16(a0,b0,acc[0][0],0,0,0);
        acc[0][1]=MFMA16(a0,b1,acc[0][1],0,0,0);
        acc[1][0]=MFMA16(a1,b0,acc[1][0],0,0,0);
        acc[1][1]=MFMA16(a1,b1,acc[1][1],0,0,0);
    }
    #pragma unroll
    for(int mi=0;mi<2;mi++)
        #pragma unroll
        for(int nj=0;nj<2;nj++)
            #pragma unroll
            for(int r=0;r<4;r++){
                int m=m0+mi*16+kg*4+r;
                int n=n0+nj*16+la;
                float val=acc[mi][nj][r];
                if(n<256) xs[(size_t)m*C_+n]=val;
                else      z [(size_t)m*C_+(n-256)]=val;
            }
}

// ---------------- MFMA GEMM + residual: t[m][n] += y2b[m][k] * Wt[n][k] ----------------
__global__ __launch_bounds__(256) void k_gemm_out(
    const unsigned short* __restrict__ Ab, const unsigned short* __restrict__ Wb,
    float* __restrict__ t)
{
    int wv=threadIdx.x>>6, lane=threadIdx.x&63;
    int m0=blockIdx.x*64+(wv>>1)*32;
    int n0=blockIdx.y*64+(wv&1)*32;
    int la=lane&15, kg=lane>>4;
    f32x4 acc[2][2];
    #pragma unroll
    for(int i=0;i<2;i++)
        #pragma unroll
        for(int j=0;j<2;j++) acc[i][j]=(f32x4){0.f,0.f,0.f,0.f};
    const unsigned short* a0p=Ab+(size_t)(m0+la)*C_+kg*8;
    const unsigned short* a1p=Ab+(size_t)(m0+16+la)*C_+kg*8;
    const unsigned short* b0p=Wb+(size_t)(n0+la)*C_+kg*8;
    const unsigned short* b1p=Wb+(size_t)(n0+16+la)*C_+kg*8;
    #pragma unroll
    for(int kk=0;kk<C_;kk+=32){
        bf16x8 a0=*(const bf16x8*)(a0p+kk);
        bf16x8 a1=*(const bf16x8*)(a1p+kk);
        bf16x8 b0=*(const bf16x8*)(b0p+kk);
        bf16x8 b1=*(const bf16x8*)(b1p+kk);
        acc[0][0]=MFMA16(a0,b0,acc[0][0],0,0,0);
        acc[0][1]=MFMA16(a0,b1,acc[0][1],0,0,0);
        acc[1][0]=MFMA16(a1,b0,acc[1][0],0,0,0);
        acc[1][1]=MFMA16(a1,b1,acc[1][1],0,0,0);
    }
    #pragma unroll
    for(int mi=0;mi<2;mi++)
        #pragma unroll
        for(int nj=0;nj<2;nj++)
            #pragma unroll
            for(int r=0;r<4;r++){
                int m=m0+mi*16+kg*4+r;
                int n=n0+nj*16+la;
                float* tp=t+(size_t)m*C_+n;
                *tp=*tp+acc[mi][nj][r];
            }
}

// ---------------- MFMA GEMM: BC[m][0:32] = seqb[m][k] * xwb[16+n][k] ----------------
__global__ __launch_bounds__(256) void k_gemm_x(
    const unsigned short* __restrict__ Ab, const unsigned short* __restrict__ Wb,
    float* __restrict__ BC)
{
    int wv=threadIdx.x>>6, lane=threadIdx.x&63;
    int m0=blockIdx.x*128+wv*32;
    int la=lane&15, kg=lane>>4;
    f32x4 acc[2][2];
    #pragma unroll
    for(int i=0;i<2;i++)
        #pragma unroll
        for(int j=0;j<2;j++) acc[i][j]=(f32x4){0.f,0.f,0.f,0.f};
    const unsigned short* a0p=Ab+(size_t)(m0+la)*C_+kg*8;
    const unsigned short* a1p=Ab+(size_t)(m0+16+la)*C_+kg*8;
    const unsigned short* b0p=Wb+(size_t)(16+la)*C_+kg*8;   // B rows of xproj_w
    const unsigned short* b1p=Wb+(size_t)(32+la)*C_+kg*8;   // C rows
    #pragma unroll
    for(int kk=0;kk<C_;kk+=32){
        bf16x8 a0=*(const bf16x8*)(a0p+kk);
        bf16x8 a1=*(const bf16x8*)(a1p+kk);
        bf16x8 b0=*(const bf16x8*)(b0p+kk);
        bf16x8 b1=*(const bf16x8*)(b1p+kk);
        acc[0][0]=MFMA16(a0,b0,acc[0][0],0,0,0);
        acc[0][1]=MFMA16(a0,b1,acc[0][1],0,0,0);
        acc[1][0]=MFMA16(a1,b0,acc[1][0],0,0,0);
        acc[1][1]=MFMA16(a1,b1,acc[1][1],0,0,0);
    }
    #pragma unroll
    for(int mi=0;mi<2;mi++)
        #pragma unroll
        for(int nj=0;nj<2;nj++)
            #pragma unroll
            for(int r=0;r<4;r++){
                int m=m0+mi*16+kg*4+r;
                BC[(size_t)m*32 + nj*16+la]=acc[mi][nj][r];
            }
}

// ---------------- MFMA GEMM: dt[m][c] = softplus(seqb[m][k]*wdtb[c][k] + dt_b[c]) ----------------
__global__ __launch_bounds__(256) void k_gemm_dt(
    const unsigned short* __restrict__ Ab, const unsigned short* __restrict__ Wb,
    const float* __restrict__ dtbias, float* __restrict__ dt)
{
    int wv=threadIdx.x>>6, lane=threadIdx.x&63;
    int m0=blockIdx.x*64+(wv>>1)*32;
    int n0=blockIdx.y*64+(wv&1)*32;
    int la=lane&15, kg=lane>>4;
    f32x4 acc[2][2];
    #pragma unroll
    for(int i=0;i<2;i++)
        #pragma unroll
        for(int j=0;j<2;j++) acc[i][j]=(f32x4){0.f,0.f,0.f,0.f};
    const unsigned short* a0p=Ab+(size_t)(m0+la)*C_+kg*8;
    const unsigned short* a1p=Ab+(size_t)(m0+16+la)*C_+kg*8;
    const unsigned short* b0p=Wb+(size_t)(n0+la)*C_+kg*8;
    const unsigned short* b1p=Wb+(size_t)(n0+16+la)*C_+kg*8;
    #pragma unroll
    for(int kk=0;kk<C_;kk+=32){
        bf16x8 a0=*(const bf16x8*)(a0p+kk);
        bf16x8 a1=*(const bf16x8*)(a1p+kk);
        bf16x8 b0=*(const bf16x8*)(b0p+kk);
        bf16x8 b1=*(const bf16x8*)(b1p+kk);
        acc[0][0]=MFMA16(a0,b0,acc[0][0],0,0,0);
        acc[0][1]=MFMA16(a0,b1,acc[0][1],0,0,0);
        acc[1][0]=MFMA16(a1,b0,acc[1][0],0,0,0);
        acc[1][1]=MFMA16(a1,b1,acc[1][1],0,0,0);
    }
    float bias0=dtbias[n0+la], bias1=dtbias[n0+16+la];
    #pragma unroll
    for(int mi=0;mi<2;mi++)
        #pragma unroll
        for(int nj=0;nj<2;nj++)
            #pragma unroll
            for(int r=0;r<4;r++){
                int m=m0+mi*16+kg*4+r;
                int n=n0+nj*16+la;
                float val=acc[mi][nj][r]+((nj==0)?bias0:bias1);
                dt[(size_t)m*C_+n]=softplus_(val);
            }
}

// ---------------- depthwise conv3x3x3 + bias + SiLU + flip-write -> seq (fp32) + seqb (bf16) ----------------
__global__ __launch_bounds__(256) void k_conv(
    const float* __restrict__ xs, const float* __restrict__ cw,
    const float* __restrict__ cb, float* __restrict__ seq,
    unsigned short* __restrict__ seqb, int ori)
{
    __shared__ float wl[256*27];
    int tid=threadIdx.x;
    for(int j=tid;j<256*27;j+=256) wl[j]=cw[j];
    int bl=blockIdx.x;
    int b=bl>>12, l=bl&4095;
    int d=l&15, w=(l>>4)&15, h=l>>8;
    __syncthreads();
    const float* base=xs+((size_t)b*L_)*C_+tid;
    const float* wp=wl+tid*27;
    float acc=cb[tid];
    #pragma unroll
    for(int kh=0;kh<3;kh++){
        int hh=h+kh-1; if((unsigned)hh>=16u) continue;
        #pragma unroll
        for(int kw=0;kw<3;kw++){
            int ww=w+kw-1; if((unsigned)ww>=16u) continue;
            #pragma unroll
            for(int kd=0;kd<3;kd++){
                int dd=d+kd-1; if((unsigned)dd>=16u) continue;
                acc=fmaf(wp[(kh*3+kw)*3+kd], base[(size_t)((hh*16+ww)*16+dd)*C_], acc);
            }
        }
    }
    acc=silu_(acc);
    int hf=(ori&1)?15-h:h;
    int wf=(ori&2)?15-w:w;
    int df=(ori&4)?15-d:d;
    size_t oidx=((size_t)b*L_+(hf*16+wf)*16+df)*C_+tid;
    seq[oidx]=acc;
    seqb[oidx]=f2b_(acc);
}

// ---------------- chunked selective scan (corner-turn tiles, no transposed arrays) ----------------
// block = 256 thr = 4 waves; block covers 16 channels (pairs p0..p0+15) x one chunk of 64 steps
__global__ __launch_bounds__(256) void k_scan1(
    const float* __restrict__ seqx, const float* __restrict__ dtlc,
    const float* __restrict__ BC, const float* __restrict__ A_log,
    float* __restrict__ Ap, float* __restrict__ Ho)
{
    __shared__ float2 dxL[64][17];
    int tid=threadIdx.x;
    int blk=blockIdx.x, cg=blk>>6, ck=blk&63;
    int p0=cg*16, b=p0>>8, c0=p0&255;
    int l0=ck*CL_;
    {
        int l=tid>>2, c4=tid&3;
        size_t base=((size_t)(b*L_+l0+l))*C_ + c0 + c4*4;
        float4 x4=*(const float4*)(seqx+base);
        float4 d4=*(const float4*)(dtlc+base);
        dxL[l][c4*4+0]=make_float2(d4.x,x4.x);
        dxL[l][c4*4+1]=make_float2(d4.y,x4.y);
        dxL[l][c4*4+2]=make_float2(d4.z,x4.z);
        dxL[l][c4*4+3]=make_float2(d4.w,x4.w);
    }
    __syncthreads();
    int wv=tid>>6, lane=tid&63, grp=lane>>4, n=lane&15;
    int cl=wv*4+grp, pair=p0+cl, c=c0+cl;
    float An=-__expf(A_log[c*16+n]);
    const float* bcp=BC+((size_t)(b*L_+l0))*32;
    float carry=0.f, sdt=0.f;
    #pragma unroll 8
    for(int l=0;l<CL_;l++){
        float2 dx=dxL[l][cl];
        float bv=bcp[l*32+n];
        float dA=__expf(dx.x*An);
        carry=fmaf(dA,carry,dx.x*bv*dx.y);
        sdt+=dx.x;
    }
    int idx=(pair*CK_+ck)*16+n;
    Ap[idx]=__expf(An*sdt); Ho[idx]=carry;
}

__global__ __launch_bounds__(256) void k_scan2(
    const float* __restrict__ Ap, const float* __restrict__ Ho, float* __restrict__ Sb)
{
    int gid=blockIdx.x*256+threadIdx.x;
    int pair=gid>>4, n=gid&15;
    float S=0.f;
    #pragma unroll
    for(int ck=0;ck<CK_;ck++){
        int idx=(pair*CK_+ck)*16+n;
        Sb[idx]=S;
        S=fmaf(Ap[idx],S,Ho[idx]);
    }
}

__global__ __launch_bounds__(256) void k_scan3(
    const float* __restrict__ seqx, const float* __restrict__ dtlc,
    const float* __restrict__ BC, const float* __restrict__ A_log,
    const float* __restrict__ Dsk, const float* __restrict__ Sb,
    float* __restrict__ y)   // y == seqx: in-place, block regions are disjoint
{
    __shared__ float2 dxL[64][17];
    __shared__ float  yL[64][17];
    int tid=threadIdx.x;
    int blk=blockIdx.x, cg=blk>>6, ck=blk&63;
    int p0=cg*16, b=p0>>8, c0=p0&255;
    int l0=ck*CL_;
    {
        int l=tid>>2, c4=tid&3;
        size_t base=((size_t)(b*L_+l0+l))*C_ + c0 + c4*4;
        float4 x4=*(const float4*)(seqx+base);
        float4 d4=*(const float4*)(dtlc+base);
        dxL[l][c4*4+0]=make_float2(d4.x,x4.x);
        dxL[l][c4*4+1]=make_float2(d4.y,x4.y);
        dxL[l][c4*4+2]=make_float2(d4.z,x4.z);
        dxL[l][c4*4+3]=make_float2(d4.w,x4.w);
    }
    __syncthreads();
    int wv=tid>>6, lane=tid&63, grp=lane>>4, n=lane&15;
    int cl=wv*4+grp, pair=p0+cl, c=c0+cl;
    float An=-__expf(A_log[c*16+n]);
    float Dc=Dsk[c];
    const float* bcp=BC+((size_t)(b*L_+l0))*32;
    float carry=Sb[(pair*CK_+ck)*16+n];
    #pragma unroll 8
    for(int l=0;l<CL_;l++){
        float2 dx=dxL[l][cl];
        float bv=bcp[l*32+n];
        float cv=bcp[l*32+16+n];
        float dA=__expf(dx.x*An);
        carry=fmaf(dA,carry,dx.x*bv*dx.y);
        float part=carry*cv;
        part+=__shfl_xor(part,1);
        part+=__shfl_xor(part,2);
        part+=__shfl_xor(part,4);
        part+=__shfl_xor(part,8);
        if(n==0) yL[l][cl]=fmaf(Dc,dx.y,part);
    }
    __syncthreads();
    {
        int l=tid>>2, c4=tid&3;
        size_t base=((size_t)(b*L_+l0+l))*C_ + c0 + c4*4;
        float4 o=make_float4(yL[l][c4*4+0],yL[l][c4*4+1],yL[l][c4*4+2],yL[l][c4*4+3]);
        *(float4*)(y+base)=o;
    }
}

// ---------------- unflip + out-LN + gate by SiLU(z) -> y2b (bf16) ----------------
__global__ __launch_bounds__(256) void k_post(
    const float* __restrict__ y, const float* __restrict__ z,
    const float* __restrict__ og, const float* __restrict__ ob,
    unsigned short* __restrict__ y2b, int ori)
{
    __shared__ float red[8];
    int c=threadIdx.x;
    int bl=blockIdx.x, b=bl>>12, l=bl&4095;
    int d=l&15, w=(l>>4)&15, h=l>>8;
    int hf=(ori&1)?15-h:h, wf=(ori&2)?15-w:w, df=(ori&4)?15-d:d;
    int lf=(hf*16+wf)*16+df;
    float v=y[((size_t)b*L_+lf)*C_+c];
    float s=v, ss=v*v;
    #pragma unroll
    for(int m=32;m>=1;m>>=1){ s+=__shfl_xor(s,m); ss+=__shfl_xor(ss,m); }
    if((c&63)==0){ red[(c>>6)*2]=s; red[(c>>6)*2+1]=ss; }
    __syncthreads();
    s=red[0]+red[2]+red[4]+red[6];
    ss=red[1]+red[3]+red[5]+red[7];
    float mn=s*(1.f/256.f);
    float rstd=rsqrtf(ss*(1.f/256.f)-mn*mn+1e-5f);
    float yn=(v-mn)*rstd*og[c]+ob[c];
    float zv=z[((size_t)b*L_+l)*C_+c];
    y2b[((size_t)b*L_+l)*C_+c]=f2b_(yn*silu_(zv));
}

// ---------------- final LN + transpose out ----------------
__global__ __launch_bounds__(256) void k_final(
    const float* __restrict__ t, const float* __restrict__ pg,
    const float* __restrict__ pb, float* __restrict__ out)
{
    __shared__ float tile[16*257];
    __shared__ float mrs[16][2];
    int blk=blockIdx.x, b=blk>>8, d=(blk>>4)&15, h=blk&15;
    int tid=threadIdx.x;
    for(int w2=0;w2<16;w2++){
        tile[w2*257+tid]=t[((size_t)b*L_+(h*16+w2)*16+d)*C_+tid];
    }
    __syncthreads();
    int r=tid>>4, p=tid&15;
    float s=0.f, ss=0.f;
    #pragma unroll
    for(int k=0;k<16;k++){ float v=tile[r*257+k*16+p]; s+=v; ss+=v*v; }
    #pragma unroll
    for(int m=1;m<16;m<<=1){ s+=__shfl_xor(s,m); ss+=__shfl_xor(ss,m); }
    if(p==0){ float mn=s*(1.f/256.f); mrs[r][0]=mn; mrs[r][1]=rsqrtf(ss*(1.f/256.f)-mn*mn+1e-5f); }
    __syncthreads();
    int w2=tid&15;
    for(int p2=0;p2<16;p2++){
        int c=(tid>>4)+16*p2;
        float v=tile[w2*257+c];
        float vn=(v-mrs[w2][0])*mrs[w2][1]*pg[c]+pb[c];
        out[((size_t)(b*C_+c))*4096 + d*256 + h*16 + w2]=vn;
    }
}

extern "C" void kernel_launch(void* const* d_in, const int* in_sizes, int n_in,
                              void* d_out, int out_size, void* d_ws, size_t ws_size,
                              hipStream_t stream)
{
    (void)in_sizes; (void)n_in; (void)out_size; (void)ws_size;
    const float* x      =(const float*)d_in[0];
    const float* in_w   =(const float*)d_in[1];
    const float* conv_w =(const float*)d_in[2];
    const float* conv_b =(const float*)d_in[3];
    const float* xproj_w=(const float*)d_in[4];
    const float* dt_w   =(const float*)d_in[5];
    const float* dt_b   =(const float*)d_in[6];
    const float* A_log  =(const float*)d_in[7];
    const float* D_skip =(const float*)d_in[8];
    const float* on_g   =(const float*)d_in[9];
    const float* on_b   =(const float*)d_in[10];
    const float* out_w  =(const float*)d_in[11];
    const float* ln1_g  =(const float*)d_in[12];
    const float* ln1_b  =(const float*)d_in[13];
    const float* post_g =(const float*)d_in[14];
    const float* post_b =(const float*)d_in[15];
    float* out=(float*)d_out;
    float* ws=(float*)d_ws;

    const size_t NBL=(size_t)BL_*C_;     // 2,097,152 elems
    float* t    = ws;                     // residual stream [B][L][C]
    float* xs   = ws +   NBL;             // conv input; reused as dtlc after conv
    float* z    = ws + 2*NBL;
    float* seq  = ws + 3*NBL;             // conv output [l][c] fp32; scan3 writes y in-place
    float* BC   = ws + 4*NBL;             // [B*L][32] fp32 (Bm | Cm)
    float* Ap   = BC + (size_t)BL_*32;
    float* Ho   = Ap + 512*CK_*16;
    float* Sb   = Ho + 512*CK_*16;
    unsigned short* hb   = (unsigned short*)(Sb + 512*CK_*16);  // bf16 LN'd activations
    unsigned short* seqb = hb   + NBL;                          // bf16 conv output
    unsigned short* y2b  = seqb + NBL;                          // bf16 gated output
    unsigned short* wbI  = y2b  + NBL;                          // bf16 in_w  (4*512*256)
    unsigned short* wbO  = wbI + (size_t)DEPTH_*512*C_;         // bf16 out_w (4*256*256)
    unsigned short* xwb  = wbO + (size_t)DEPTH_*C_*C_;          // bf16 xproj_w (4*48*256)
    unsigned short* wdtb = xwb + (size_t)DEPTH_*48*C_;          // bf16 W_eff (4*256*256)
    float* dtlc = xs;                     // dt[l][c] fp32 — aliases xs (dead after conv)

    k_w2b<<<DEPTH_*512*C_/1024,256,0,stream>>>(in_w, wbI);
    k_w2b<<<DEPTH_*C_*C_/1024,256,0,stream>>>(out_w, wbO);
    k_w2b<<<DEPTH_*48*C_/1024,256,0,stream>>>(xproj_w, xwb);
    k_wdt<<<DEPTH_*C_,256,0,stream>>>(dt_w, xproj_w, wdtb);
    k_t_in<<<512,256,0,stream>>>(x,t);
    for(int i=0;i<DEPTH_;i++){
        int ori=i&7;
        k_ln<<<2048,256,0,stream>>>(t, ln1_g+i*256, ln1_b+i*256, hb);
        k_gemm_in<<<dim3(128,8),256,0,stream>>>(hb, wbI+(size_t)i*512*C_, xs, z);
        k_conv<<<8192,256,0,stream>>>(xs, conv_w+(size_t)i*6912, conv_b+i*256, seq, seqb, ori);
        k_gemm_x<<<64,256,0,stream>>>(seqb, xwb+(size_t)i*48*C_, BC);
        k_gemm_dt<<<dim3(128,4),256,0,stream>>>(seqb, wdtb+(size_t)i*C_*C_, dt_b+i*256, dtlc);
        k_scan1<<<2048,256,0,stream>>>(seq, dtlc, BC, A_log+(size_t)i*4096, Ap, Ho);
        k_scan2<<<32,256,0,stream>>>(Ap, Ho, Sb);
        k_scan3<<<2048,256,0,stream>>>(seq, dtlc, BC, A_log+(size_t)i*4096, D_skip+i*256, Sb, seq);
        k_post<<<8192,256,0,stream>>>(seq, z, on_g+i*256, on_b+i*256, y2b, ori);
        k_gemm_out<<<dim3(128,4),256,0,stream>>>(y2b, wbO+(size_t)i*C_*C_, t);
    }
    k_final<<<512,256,0,stream>>>(t, post_g, post_b, out);
}

// Round 9
// 610.408 us; speedup vs baseline: 1.4069x; 1.2288x over previous
//
#include <hip/hip_runtime.h>
#include <math.h>

#define B_ 2
#define C_ 256
#define L_ 4096
#define BL_ 8192
#define DEPTH_ 4
#define CK_ 64   // chunks per sequence
#define CL_ 64   // chunk length

typedef __attribute__((ext_vector_type(8))) short bf16x8;
typedef __attribute__((ext_vector_type(4))) float f32x4;
#define MFMA16 __builtin_amdgcn_mfma_f32_16x16x32_bf16

__device__ __forceinline__ float silu_(float x){ return x/(1.f+__expf(-x)); }
__device__ __forceinline__ float softplus_(float x){ return fmaxf(x,0.f)+log1pf(__expf(-fabsf(x))); }
__device__ __forceinline__ unsigned short f2b_(float f){
    union{float f;unsigned u;}v; v.f=f;
    unsigned r=(v.u + 0x7fffu + ((v.u>>16)&1u))>>16;
    return (unsigned short)r;
}

// ---------------- fp32 -> bf16 weight conversion ----------------
__global__ __launch_bounds__(256) void k_w2b(const float* __restrict__ src, unsigned short* __restrict__ dst)
{
    int i=blockIdx.x*256+threadIdx.x;
    float4 v=((const float4*)src)[i];
    ushort4 o; o.x=f2b_(v.x); o.y=f2b_(v.y); o.z=f2b_(v.z); o.w=f2b_(v.w);
    ((ushort4*)dst)[i]=o;
}

// ---------------- composed dt weight: W_eff[i][c][k] = sum_j dt_w[i][c][j]*xw[i][j][k] -> bf16 ----------------
__global__ __launch_bounds__(256) void k_wdt(
    const float* __restrict__ dtw, const float* __restrict__ xw,
    unsigned short* __restrict__ wdtb)
{
    int blk=blockIdx.x;          // i*256 + c
    int i=blk>>8, c=blk&255, k=threadIdx.x;
    const float* dr=dtw+((size_t)i*C_+c)*16;
    const float* xr=xw+(size_t)i*48*C_+k;
    float acc=0.f;
    #pragma unroll
    for(int j=0;j<16;j++) acc=fmaf(dr[j], xr[(size_t)j*C_], acc);
    wdtb[((size_t)i*C_+c)*C_+k]=f2b_(acc);
}

// ---------------- transpose in: x (B,C,D,H,W) -> t [B][L][C], l=(h*16+w)*16+d ----------------
__global__ __launch_bounds__(256) void k_t_in(const float* __restrict__ x, float* __restrict__ t)
{
    __shared__ float tile[16*257];
    int blk=blockIdx.x, b=blk>>8, d=(blk>>4)&15, h=blk&15;
    int tid=threadIdx.x;
    int w2=tid&15;
    for(int p=0;p<16;p++){
        int c=(tid>>4)+16*p;
        tile[w2*257+c]=x[((size_t)(b*C_+c))*4096 + d*256 + h*16 + w2];
    }
    __syncthreads();
    for(int k=0;k<16;k++){
        t[((size_t)b*L_+(h*16+k)*16+d)*C_+tid]=tile[k*257+tid];
    }
}

// ---------------- LN1: t -> hb (bf16 [M][256]) ----------------
__global__ __launch_bounds__(256) void k_ln(
    const float* __restrict__ t, const float* __restrict__ g,
    const float* __restrict__ be, unsigned short* __restrict__ hb)
{
    int wv=threadIdx.x>>6, lane=threadIdx.x&63;
    int row=blockIdx.x*4+wv;
    float4 v=((const float4*)(t+(size_t)row*C_))[lane];
    float s=v.x+v.y+v.z+v.w;
    float ss=v.x*v.x+v.y*v.y+v.z*v.z+v.w*v.w;
    #pragma unroll
    for(int m=1;m<64;m<<=1){ s+=__shfl_xor(s,m); ss+=__shfl_xor(ss,m); }
    float mn=s*(1.f/256.f);
    float rs=rsqrtf(ss*(1.f/256.f)-mn*mn+1e-5f);
    float4 gg=((const float4*)g)[lane];
    float4 bb=((const float4*)be)[lane];
    ushort4 o;
    o.x=f2b_((v.x-mn)*rs*gg.x+bb.x);
    o.y=f2b_((v.y-mn)*rs*gg.y+bb.y);
    o.z=f2b_((v.z-mn)*rs*gg.z+bb.z);
    o.w=f2b_((v.w-mn)*rs*gg.w+bb.w);
    ((ushort4*)(hb+(size_t)row*C_))[lane]=o;
}

// ---------------- MFMA GEMM: xs|z[m][n] = hb[m][k] * Wt[n][k] ; N=512 split ----------------
__global__ __launch_bounds__(256) void k_gemm_in(
    const unsigned short* __restrict__ Ab, const unsigned short* __restrict__ Wb,
    float* __restrict__ xs, float* __restrict__ z)
{
    int wv=threadIdx.x>>6, lane=threadIdx.x&63;
    int m0=blockIdx.x*64+(wv>>1)*32;
    int n0=blockIdx.y*64+(wv&1)*32;
    int la=lane&15, kg=lane>>4;
    f32x4 acc[2][2];
    #pragma unroll
    for(int i=0;i<2;i++)
        #pragma unroll
        for(int j=0;j<2;j++) acc[i][j]=(f32x4){0.f,0.f,0.f,0.f};
    const unsigned short* a0p=Ab+(size_t)(m0+la)*C_+kg*8;
    const unsigned short* a1p=Ab+(size_t)(m0+16+la)*C_+kg*8;
    const unsigned short* b0p=Wb+(size_t)(n0+la)*C_+kg*8;
    const unsigned short* b1p=Wb+(size_t)(n0+16+la)*C_+kg*8;
    #pragma unroll
    for(int kk=0;kk<C_;kk+=32){
        bf16x8 a0=*(const bf16x8*)(a0p+kk);
        bf16x8 a1=*(const bf16x8*)(a1p+kk);
        bf16x8 b0=*(const bf16x8*)(b0p+kk);
        bf16x8 b1=*(const bf16x8*)(b1p+kk);
        acc[0][0]=MFMA16(a0,b0,acc[0][0],0,0,0);
        acc[0][1]=MFMA16(a0,b1,acc[0][1],0,0,0);
        acc[1][0]=MFMA16(a1,b0,acc[1][0],0,0,0);
        acc[1][1]=MFMA16(a1,b1,acc[1][1],0,0,0);
    }
    #pragma unroll
    for(int mi=0;mi<2;mi++)
        #pragma unroll
        for(int nj=0;nj<2;nj++)
            #pragma unroll
            for(int r=0;r<4;r++){
                int m=m0+mi*16+kg*4+r;
                int n=n0+nj*16+la;
                float val=acc[mi][nj][r];
                if(n<256) xs[(size_t)m*C_+n]=val;
                else      z [(size_t)m*C_+(n-256)]=val;
            }
}

// ---------------- MFMA GEMM + residual: t[m][n] += y2b[m][k] * Wt[n][k] ----------------
__global__ __launch_bounds__(256) void k_gemm_out(
    const unsigned short* __restrict__ Ab, const unsigned short* __restrict__ Wb,
    float* __restrict__ t)
{
    int wv=threadIdx.x>>6, lane=threadIdx.x&63;
    int m0=blockIdx.x*64+(wv>>1)*32;
    int n0=blockIdx.y*64+(wv&1)*32;
    int la=lane&15, kg=lane>>4;
    f32x4 acc[2][2];
    #pragma unroll
    for(int i=0;i<2;i++)
        #pragma unroll
        for(int j=0;j<2;j++) acc[i][j]=(f32x4){0.f,0.f,0.f,0.f};
    const unsigned short* a0p=Ab+(size_t)(m0+la)*C_+kg*8;
    const unsigned short* a1p=Ab+(size_t)(m0+16+la)*C_+kg*8;
    const unsigned short* b0p=Wb+(size_t)(n0+la)*C_+kg*8;
    const unsigned short* b1p=Wb+(size_t)(n0+16+la)*C_+kg*8;
    #pragma unroll
    for(int kk=0;kk<C_;kk+=32){
        bf16x8 a0=*(const bf16x8*)(a0p+kk);
        bf16x8 a1=*(const bf16x8*)(a1p+kk);
        bf16x8 b0=*(const bf16x8*)(b0p+kk);
        bf16x8 b1=*(const bf16x8*)(b1p+kk);
        acc[0][0]=MFMA16(a0,b0,acc[0][0],0,0,0);
        acc[0][1]=MFMA16(a0,b1,acc[0][1],0,0,0);
        acc[1][0]=MFMA16(a1,b0,acc[1][0],0,0,0);
        acc[1][1]=MFMA16(a1,b1,acc[1][1],0,0,0);
    }
    #pragma unroll
    for(int mi=0;mi<2;mi++)
        #pragma unroll
        for(int nj=0;nj<2;nj++)
            #pragma unroll
            for(int r=0;r<4;r++){
                int m=m0+mi*16+kg*4+r;
                int n=n0+nj*16+la;
                float* tp=t+(size_t)m*C_+n;
                *tp=*tp+acc[mi][nj][r];
            }
}

// ---------------- MFMA GEMM: BC[m][0:32] = seqb[m][k] * xwb[16+n][k] ----------------
__global__ __launch_bounds__(256) void k_gemm_x(
    const unsigned short* __restrict__ Ab, const unsigned short* __restrict__ Wb,
    float* __restrict__ BC)
{
    int wv=threadIdx.x>>6, lane=threadIdx.x&63;
    int m0=blockIdx.x*128+wv*32;
    int la=lane&15, kg=lane>>4;
    f32x4 acc[2][2];
    #pragma unroll
    for(int i=0;i<2;i++)
        #pragma unroll
        for(int j=0;j<2;j++) acc[i][j]=(f32x4){0.f,0.f,0.f,0.f};
    const unsigned short* a0p=Ab+(size_t)(m0+la)*C_+kg*8;
    const unsigned short* a1p=Ab+(size_t)(m0+16+la)*C_+kg*8;
    const unsigned short* b0p=Wb+(size_t)(16+la)*C_+kg*8;   // B rows of xproj_w
    const unsigned short* b1p=Wb+(size_t)(32+la)*C_+kg*8;   // C rows
    #pragma unroll
    for(int kk=0;kk<C_;kk+=32){
        bf16x8 a0=*(const bf16x8*)(a0p+kk);
        bf16x8 a1=*(const bf16x8*)(a1p+kk);
        bf16x8 b0=*(const bf16x8*)(b0p+kk);
        bf16x8 b1=*(const bf16x8*)(b1p+kk);
        acc[0][0]=MFMA16(a0,b0,acc[0][0],0,0,0);
        acc[0][1]=MFMA16(a0,b1,acc[0][1],0,0,0);
        acc[1][0]=MFMA16(a1,b0,acc[1][0],0,0,0);
        acc[1][1]=MFMA16(a1,b1,acc[1][1],0,0,0);
    }
    #pragma unroll
    for(int mi=0;mi<2;mi++)
        #pragma unroll
        for(int nj=0;nj<2;nj++)
            #pragma unroll
            for(int r=0;r<4;r++){
                int m=m0+mi*16+kg*4+r;
                BC[(size_t)m*32 + nj*16+la]=acc[mi][nj][r];
            }
}

// ---------------- MFMA GEMM: dt[m][c] = softplus(seqb[m][k]*wdtb[c][k] + dt_b[c]) ----------------
__global__ __launch_bounds__(256) void k_gemm_dt(
    const unsigned short* __restrict__ Ab, const unsigned short* __restrict__ Wb,
    const float* __restrict__ dtbias, float* __restrict__ dt)
{
    int wv=threadIdx.x>>6, lane=threadIdx.x&63;
    int m0=blockIdx.x*64+(wv>>1)*32;
    int n0=blockIdx.y*64+(wv&1)*32;
    int la=lane&15, kg=lane>>4;
    f32x4 acc[2][2];
    #pragma unroll
    for(int i=0;i<2;i++)
        #pragma unroll
        for(int j=0;j<2;j++) acc[i][j]=(f32x4){0.f,0.f,0.f,0.f};
    const unsigned short* a0p=Ab+(size_t)(m0+la)*C_+kg*8;
    const unsigned short* a1p=Ab+(size_t)(m0+16+la)*C_+kg*8;
    const unsigned short* b0p=Wb+(size_t)(n0+la)*C_+kg*8;
    const unsigned short* b1p=Wb+(size_t)(n0+16+la)*C_+kg*8;
    #pragma unroll
    for(int kk=0;kk<C_;kk+=32){
        bf16x8 a0=*(const bf16x8*)(a0p+kk);
        bf16x8 a1=*(const bf16x8*)(a1p+kk);
        bf16x8 b0=*(const bf16x8*)(b0p+kk);
        bf16x8 b1=*(const bf16x8*)(b1p+kk);
        acc[0][0]=MFMA16(a0,b0,acc[0][0],0,0,0);
        acc[0][1]=MFMA16(a0,b1,acc[0][1],0,0,0);
        acc[1][0]=MFMA16(a1,b0,acc[1][0],0,0,0);
        acc[1][1]=MFMA16(a1,b1,acc[1][1],0,0,0);
    }
    float bias0=dtbias[n0+la], bias1=dtbias[n0+16+la];
    #pragma unroll
    for(int mi=0;mi<2;mi++)
        #pragma unroll
        for(int nj=0;nj<2;nj++)
            #pragma unroll
            for(int r=0;r<4;r++){
                int m=m0+mi*16+kg*4+r;
                int n=n0+nj*16+la;
                float val=acc[mi][nj][r]+((nj==0)?bias0:bias1);
                dt[(size_t)m*C_+n]=softplus_(val);
            }
}

// ---------------- depthwise conv3x3x3, register-blocked along d ----------------
// block = (b,h,w), thread = channel c, 16 d-outputs per thread.
// loads/output: 27 -> ~9; 16 independent acc chains hide L2 latency.
__global__ __launch_bounds__(256) void k_conv(
    const float* __restrict__ xs, const float* __restrict__ cw,
    const float* __restrict__ cb, float* __restrict__ seq,
    unsigned short* __restrict__ seqb, int ori)
{
    __shared__ float wl[256*27];
    int tid=threadIdx.x;
    for(int j=tid;j<256*27;j+=256) wl[j]=cw[j];
    int blk=blockIdx.x;          // b*256 + h*16 + w
    int b=blk>>8, h=(blk>>4)&15, w=blk&15;
    __syncthreads();
    const float* wp=wl+tid*27;
    float bias=cb[tid];
    float acc[16];
    #pragma unroll
    for(int d=0;d<16;d++) acc[d]=bias;
    #pragma unroll
    for(int kh=0;kh<3;kh++){
        int hh=h+kh-1; if((unsigned)hh>=16u) continue;
        #pragma unroll
        for(int kw=0;kw<3;kw++){
            int ww=w+kw-1; if((unsigned)ww>=16u) continue;
            const float* bp=xs+((size_t)(b*L_)+(hh*16+ww)*16)*C_+tid;
            float w0=wp[(kh*3+kw)*3+0];
            float w1=wp[(kh*3+kw)*3+1];
            float w2=wp[(kh*3+kw)*3+2];
            // in[dd] feeds out[dd+1](w0), out[dd](w1), out[dd-1](w2)
            #pragma unroll
            for(int dd=0;dd<16;dd++){
                float v=bp[(size_t)dd*C_];
                if(dd<15) acc[dd+1]=fmaf(w0,v,acc[dd+1]);
                acc[dd]=fmaf(w1,v,acc[dd]);
                if(dd>0)  acc[dd-1]=fmaf(w2,v,acc[dd-1]);
            }
        }
    }
    int hf=(ori&1)?15-h:h;
    int wf=(ori&2)?15-w:w;
    size_t obase=((size_t)b*L_+(hf*16+wf)*16)*C_+tid;
    #pragma unroll
    for(int d=0;d<16;d++){
        float a=silu_(acc[d]);
        int df=(ori&4)?15-d:d;
        size_t oidx=obase+(size_t)df*C_;
        seq[oidx]=a;
        seqb[oidx]=f2b_(a);
    }
}

// ---------------- chunked selective scan (corner-turn tiles, no transposed arrays) ----------------
// block = 256 thr = 4 waves; block covers 16 channels (pairs p0..p0+15) x one chunk of 64 steps
__global__ __launch_bounds__(256) void k_scan1(
    const float* __restrict__ seqx, const float* __restrict__ dtlc,
    const float* __restrict__ BC, const float* __restrict__ A_log,
    float* __restrict__ Ap, float* __restrict__ Ho)
{
    __shared__ float2 dxL[64][17];
    int tid=threadIdx.x;
    int blk=blockIdx.x, cg=blk>>6, ck=blk&63;
    int p0=cg*16, b=p0>>8, c0=p0&255;
    int l0=ck*CL_;
    {
        int l=tid>>2, c4=tid&3;
        size_t base=((size_t)(b*L_+l0+l))*C_ + c0 + c4*4;
        float4 x4=*(const float4*)(seqx+base);
        float4 d4=*(const float4*)(dtlc+base);
        dxL[l][c4*4+0]=make_float2(d4.x,x4.x);
        dxL[l][c4*4+1]=make_float2(d4.y,x4.y);
        dxL[l][c4*4+2]=make_float2(d4.z,x4.z);
        dxL[l][c4*4+3]=make_float2(d4.w,x4.w);
    }
    __syncthreads();
    int wv=tid>>6, lane=tid&63, grp=lane>>4, n=lane&15;
    int cl=wv*4+grp, pair=p0+cl, c=c0+cl;
    float An=-__expf(A_log[c*16+n]);
    const float* bcp=BC+((size_t)(b*L_+l0))*32;
    float carry=0.f, sdt=0.f;
    #pragma unroll 8
    for(int l=0;l<CL_;l++){
        float2 dx=dxL[l][cl];
        float bv=bcp[l*32+n];
        float dA=__expf(dx.x*An);
        carry=fmaf(dA,carry,dx.x*bv*dx.y);
        sdt+=dx.x;
    }
    int idx=(pair*CK_+ck)*16+n;
    Ap[idx]=__expf(An*sdt); Ho[idx]=carry;
}

__global__ __launch_bounds__(256) void k_scan2(
    const float* __restrict__ Ap, const float* __restrict__ Ho, float* __restrict__ Sb)
{
    int gid=blockIdx.x*256+threadIdx.x;
    int pair=gid>>4, n=gid&15;
    float S=0.f;
    #pragma unroll
    for(int ck=0;ck<CK_;ck++){
        int idx=(pair*CK_+ck)*16+n;
        Sb[idx]=S;
        S=fmaf(Ap[idx],S,Ho[idx]);
    }
}

__global__ __launch_bounds__(256) void k_scan3(
    const float* __restrict__ seqx, const float* __restrict__ dtlc,
    const float* __restrict__ BC, const float* __restrict__ A_log,
    const float* __restrict__ Dsk, const float* __restrict__ Sb,
    float* __restrict__ y)   // y == seqx: in-place, block regions are disjoint
{
    __shared__ float2 dxL[64][17];
    __shared__ float  yL[64][17];
    int tid=threadIdx.x;
    int blk=blockIdx.x, cg=blk>>6, ck=blk&63;
    int p0=cg*16, b=p0>>8, c0=p0&255;
    int l0=ck*CL_;
    {
        int l=tid>>2, c4=tid&3;
        size_t base=((size_t)(b*L_+l0+l))*C_ + c0 + c4*4;
        float4 x4=*(const float4*)(seqx+base);
        float4 d4=*(const float4*)(dtlc+base);
        dxL[l][c4*4+0]=make_float2(d4.x,x4.x);
        dxL[l][c4*4+1]=make_float2(d4.y,x4.y);
        dxL[l][c4*4+2]=make_float2(d4.z,x4.z);
        dxL[l][c4*4+3]=make_float2(d4.w,x4.w);
    }
    __syncthreads();
    int wv=tid>>6, lane=tid&63, grp=lane>>4, n=lane&15;
    int cl=wv*4+grp, pair=p0+cl, c=c0+cl;
    float An=-__expf(A_log[c*16+n]);
    float Dc=Dsk[c];
    const float* bcp=BC+((size_t)(b*L_+l0))*32;
    float carry=Sb[(pair*CK_+ck)*16+n];
    #pragma unroll 8
    for(int l=0;l<CL_;l++){
        float2 dx=dxL[l][cl];
        float bv=bcp[l*32+n];
        float cv=bcp[l*32+16+n];
        float dA=__expf(dx.x*An);
        carry=fmaf(dA,carry,dx.x*bv*dx.y);
        float part=carry*cv;
        part+=__shfl_xor(part,1);
        part+=__shfl_xor(part,2);
        part+=__shfl_xor(part,4);
        part+=__shfl_xor(part,8);
        if(n==0) yL[l][cl]=fmaf(Dc,dx.y,part);
    }
    __syncthreads();
    {
        int l=tid>>2, c4=tid&3;
        size_t base=((size_t)(b*L_+l0+l))*C_ + c0 + c4*4;
        float4 o=make_float4(yL[l][c4*4+0],yL[l][c4*4+1],yL[l][c4*4+2],yL[l][c4*4+3]);
        *(float4*)(y+base)=o;
    }
}

// ---------------- unflip + out-LN + gate by SiLU(z) -> y2b (bf16) ----------------
__global__ __launch_bounds__(256) void k_post(
    const float* __restrict__ y, const float* __restrict__ z,
    const float* __restrict__ og, const float* __restrict__ ob,
    unsigned short* __restrict__ y2b, int ori)
{
    __shared__ float red[8];
    int c=threadIdx.x;
    int bl=blockIdx.x, b=bl>>12, l=bl&4095;
    int d=l&15, w=(l>>4)&15, h=l>>8;
    int hf=(ori&1)?15-h:h, wf=(ori&2)?15-w:w, df=(ori&4)?15-d:d;
    int lf=(hf*16+wf)*16+df;
    float v=y[((size_t)b*L_+lf)*C_+c];
    float s=v, ss=v*v;
    #pragma unroll
    for(int m=32;m>=1;m>>=1){ s+=__shfl_xor(s,m); ss+=__shfl_xor(ss,m); }
    if((c&63)==0){ red[(c>>6)*2]=s; red[(c>>6)*2+1]=ss; }
    __syncthreads();
    s=red[0]+red[2]+red[4]+red[6];
    ss=red[1]+red[3]+red[5]+red[7];
    float mn=s*(1.f/256.f);
    float rstd=rsqrtf(ss*(1.f/256.f)-mn*mn+1e-5f);
    float yn=(v-mn)*rstd*og[c]+ob[c];
    float zv=z[((size_t)b*L_+l)*C_+c];
    y2b[((size_t)b*L_+l)*C_+c]=f2b_(yn*silu_(zv));
}

// ---------------- final LN + transpose out ----------------
__global__ __launch_bounds__(256) void k_final(
    const float* __restrict__ t, const float* __restrict__ pg,
    const float* __restrict__ pb, float* __restrict__ out)
{
    __shared__ float tile[16*257];
    __shared__ float mrs[16][2];
    int blk=blockIdx.x, b=blk>>8, d=(blk>>4)&15, h=blk&15;
    int tid=threadIdx.x;
    for(int w2=0;w2<16;w2++){
        tile[w2*257+tid]=t[((size_t)b*L_+(h*16+w2)*16+d)*C_+tid];
    }
    __syncthreads();
    int r=tid>>4, p=tid&15;
    float s=0.f, ss=0.f;
    #pragma unroll
    for(int k=0;k<16;k++){ float v=tile[r*257+k*16+p]; s+=v; ss+=v*v; }
    #pragma unroll
    for(int m=1;m<16;m<<=1){ s+=__shfl_xor(s,m); ss+=__shfl_xor(ss,m); }
    if(p==0){ float mn=s*(1.f/256.f); mrs[r][0]=mn; mrs[r][1]=rsqrtf(ss*(1.f/256.f)-mn*mn+1e-5f); }
    __syncthreads();
    int w2=tid&15;
    for(int p2=0;p2<16;p2++){
        int c=(tid>>4)+16*p2;
        float v=tile[w2*257+c];
        float vn=(v-mrs[w2][0])*mrs[w2][1]*pg[c]+pb[c];
        out[((size_t)(b*C_+c))*4096 + d*256 + h*16 + w2]=vn;
    }
}

extern "C" void kernel_launch(void* const* d_in, const int* in_sizes, int n_in,
                              void* d_out, int out_size, void* d_ws, size_t ws_size,
                              hipStream_t stream)
{
    (void)in_sizes; (void)n_in; (void)out_size; (void)ws_size;
    const float* x      =(const float*)d_in[0];
    const float* in_w   =(const float*)d_in[1];
    const float* conv_w =(const float*)d_in[2];
    const float* conv_b =(const float*)d_in[3];
    const float* xproj_w=(const float*)d_in[4];
    const float* dt_w   =(const float*)d_in[5];
    const float* dt_b   =(const float*)d_in[6];
    const float* A_log  =(const float*)d_in[7];
    const float* D_skip =(const float*)d_in[8];
    const float* on_g   =(const float*)d_in[9];
    const float* on_b   =(const float*)d_in[10];
    const float* out_w  =(const float*)d_in[11];
    const float* ln1_g  =(const float*)d_in[12];
    const float* ln1_b  =(const float*)d_in[13];
    const float* post_g =(const float*)d_in[14];
    const float* post_b =(const float*)d_in[15];
    float* out=(float*)d_out;
    float* ws=(float*)d_ws;

    const size_t NBL=(size_t)BL_*C_;     // 2,097,152 elems
    float* t    = ws;                     // residual stream [B][L][C]
    float* xs   = ws +   NBL;             // conv input; reused as dtlc after conv
    float* z    = ws + 2*NBL;
    float* seq  = ws + 3*NBL;             // conv output [l][c] fp32; scan3 writes y in-place
    float* BC   = ws + 4*NBL;             // [B*L][32] fp32 (Bm | Cm)
    float* Ap   = BC + (size_t)BL_*32;
    float* Ho   = Ap + 512*CK_*16;
    float* Sb   = Ho + 512*CK_*16;
    unsigned short* hb   = (unsigned short*)(Sb + 512*CK_*16);  // bf16 LN'd activations
    unsigned short* seqb = hb   + NBL;                          // bf16 conv output
    unsigned short* y2b  = seqb + NBL;                          // bf16 gated output
    unsigned short* wbI  = y2b  + NBL;                          // bf16 in_w  (4*512*256)
    unsigned short* wbO  = wbI + (size_t)DEPTH_*512*C_;         // bf16 out_w (4*256*256)
    unsigned short* xwb  = wbO + (size_t)DEPTH_*C_*C_;          // bf16 xproj_w (4*48*256)
    unsigned short* wdtb = xwb + (size_t)DEPTH_*48*C_;          // bf16 W_eff (4*256*256)
    float* dtlc = xs;                     // dt[l][c] fp32 — aliases xs (dead after conv)

    k_w2b<<<DEPTH_*512*C_/1024,256,0,stream>>>(in_w, wbI);
    k_w2b<<<DEPTH_*C_*C_/1024,256,0,stream>>>(out_w, wbO);
    k_w2b<<<DEPTH_*48*C_/1024,256,0,stream>>>(xproj_w, xwb);
    k_wdt<<<DEPTH_*C_,256,0,stream>>>(dt_w, xproj_w, wdtb);
    k_t_in<<<512,256,0,stream>>>(x,t);
    for(int i=0;i<DEPTH_;i++){
        int ori=i&7;
        k_ln<<<2048,256,0,stream>>>(t, ln1_g+i*256, ln1_b+i*256, hb);
        k_gemm_in<<<dim3(128,8),256,0,stream>>>(hb, wbI+(size_t)i*512*C_, xs, z);
        k_conv<<<512,256,0,stream>>>(xs, conv_w+(size_t)i*6912, conv_b+i*256, seq, seqb, ori);
        k_gemm_x<<<64,256,0,stream>>>(seqb, xwb+(size_t)i*48*C_, BC);
        k_gemm_dt<<<dim3(128,4),256,0,stream>>>(seqb, wdtb+(size_t)i*C_*C_, dt_b+i*256, dtlc);
        k_scan1<<<2048,256,0,stream>>>(seq, dtlc, BC, A_log+(size_t)i*4096, Ap, Ho);
        k_scan2<<<32,256,0,stream>>>(Ap, Ho, Sb);
        k_scan3<<<2048,256,0,stream>>>(seq, dtlc, BC, A_log+(size_t)i*4096, D_skip+i*256, Sb, seq);
        k_post<<<8192,256,0,stream>>>(seq, z, on_g+i*256, on_b+i*256, y2b, ori);
        k_gemm_out<<<dim3(128,4),256,0,stream>>>(y2b, wbO+(size_t)i*C_*C_, t);
    }
    k_final<<<512,256,0,stream>>>(t, post_g, post_b, out);
}